// Round 3
// baseline (28501.715 us; speedup 1.0000x reference)
//
#include <hip/hip_runtime.h>
#include <hip/hip_bf16.h>

typedef unsigned short u16;
typedef unsigned int u32;
typedef __attribute__((ext_vector_type(8))) short short8;
typedef __attribute__((ext_vector_type(16))) float floatx16;

#define T_ 128
#define B_ 256
#define H_ 850
#define BH (B_ * H_)          // 217600
#define SP 864                // padded K / plane column stride
#define PS (B_ * SP)          // state plane elems (221184)
#define WMS (1700 * SP)       // one transposed weight matrix elems
#define TB (T_ * B_)          // 32768 rows of the hoisted X GEMM

// ARCH pairs: (0,0),(0,1),(1,2),(1,3),(2,0),(2,1),(3,2),(4,3)
__device__ __constant__ int PRED[8]  = {0, 0, 1, 1, 2, 2, 3, 4};
__device__ __constant__ int ACTID[8] = {0, 1, 2, 3, 0, 1, 2, 3};

__device__ __forceinline__ float sigf(float x) { return 1.f / (1.f + __expf(-x)); }
__device__ __forceinline__ float actf(int a, float x) {
    if (a == 0) { float e = __expf(2.f * x); return 1.f - 2.f / (e + 1.f); } // tanh
    if (a == 1) return x > 0.f ? x : 0.f;
    if (a == 2) return sigf(x);
    return x;
}
__device__ __forceinline__ float b2f(u16 u) {
    return __uint_as_float(((u32)u) << 16);   // exact bf16 -> f32
}
__device__ __forceinline__ void split2(float x, u16& hi, u16& lo) {
    __hip_bfloat16 h = __float2bfloat16(x);
    float hf = __bfloat162float(h);
    __hip_bfloat16 l = __float2bfloat16(x - hf);
    hi = reinterpret_cast<u16&>(h);
    lo = reinterpret_cast<u16&>(l);
}

// ---- transpose + split: 10 matrices, each src [850 k][1700 n] -> WT [1700 n][864 k] hi/lo ----
// z=0: W0 rows 0..849 (x-part); z=1: W0 rows 850..1699 (h-part); z=2..9: Ws[z-2]
__global__ __launch_bounds__(256) void transpose_w(
    const float* __restrict__ W0, const float* __restrict__ WS,
    u16* __restrict__ WH, u16* __restrict__ WL)
{
    const int z = blockIdx.z;
    const float* src = (z == 0) ? W0 : (z == 1) ? (W0 + (size_t)850 * 1700)
                       : (WS + (size_t)(z - 2) * 850 * 1700);
    u16* dh = WH + (size_t)z * WMS;
    u16* dl = WL + (size_t)z * WMS;
    const int k0 = blockIdx.x * 64;   // 14 blocks -> up to 896, guarded
    const int n0 = blockIdx.y * 64;   // 27 blocks -> up to 1728, guarded

    __shared__ float tile[64][65];
    const int t = threadIdx.x;
    const int cn = t & 63;
    const int rb = (t >> 6) * 16;
#pragma unroll
    for (int j = 0; j < 16; j++) {
        const int k = k0 + rb + j;
        const int n = n0 + cn;
        float v = 0.f;
        if (k < 850 && n < 1700) v = src[(size_t)k * 1700 + n];
        tile[rb + j][cn] = v;
    }
    __syncthreads();
    const int r  = t >> 2;
    const int c0 = (t & 3) * 16;
    const int n = n0 + r;
    if (n < 1700) {
#pragma unroll
        for (int j = 0; j < 16; j += 2) {
            const int kk = k0 + c0 + j;
            if (kk < SP) {
                u16 h0, l0, h1, l1;
                split2(tile[c0 + j][r],     h0, l0);
                split2(tile[c0 + j + 1][r], h1, l1);
                *(u32*)(dh + (size_t)n * SP + kk) = (u32)h0 | ((u32)h1 << 16);
                *(u32*)(dl + (size_t)n * SP + kk) = (u32)l0 | ((u32)l1 << 16);
            }
        }
    }
}

// ---- init: split fp32 hidden into plane 9 (hi/lo), zero pad cols ----
__global__ __launch_bounds__(256) void init_kern(
    const float* __restrict__ HID, u16* __restrict__ SH, u16* __restrict__ SL)
{
    const int idx = blockIdx.x * 256 + threadIdx.x;   // over PS
    const int row = idx / SP, col = idx % SP;
    float v = (col < H_) ? HID[row * H_ + col] : 0.f;
    u16 hi, lo; split2(v, hi, lo);
    SH[9 * PS + idx] = hi;
    SL[9 * PS + idx] = lo;
}

// ---- zero the pad columns of state planes 0..8 (ws is re-poisoned every call) ----
__global__ __launch_bounds__(256) void zpad_kern(u16* __restrict__ SH, u16* __restrict__ SL)
{
    const int idx = blockIdx.x * 256 + threadIdx.x;   // 9*256*14 = 32256
    if (idx >= 9 * B_ * 14) return;
    const int p = idx / (B_ * 14);
    const int rem = idx % (B_ * 14);
    const int row = rem / 14;
    const int c = H_ + rem % 14;
    const size_t off = (size_t)p * PS + row * SP + c;
    SH[off] = 0; SL[off] = 0;
}

// ---- stage X as bf16 hi/lo planes [TB rows][SP cols] (tier A only) ----
__global__ __launch_bounds__(256) void stage_x(
    const float* __restrict__ X, u16* __restrict__ XH, u16* __restrict__ XL)
{
    const int total = TB * SP;    // 28,311,552
    for (int idx = blockIdx.x * 256 + threadIdx.x; idx < total; idx += gridDim.x * 256) {
        const int row = idx / SP;
        const int col = idx - row * SP;
        float v = (col < H_) ? X[(size_t)row * H_ + col] : 0.f;
        u16 hi, lo; split2(v, hi, lo);
        XH[idx] = hi; XL[idx] = lo;
    }
}

// ---- K-loop over bf16 hi/lo planes, ranged [k0,k1) ----
__device__ __forceinline__ void kloop_planes_rng(
    const u16* __restrict__ ah, const u16* __restrict__ al,
    const u16* __restrict__ wh, const u16* __restrict__ wl,
    int m0, int rc, int rh, int r31, int seg, int k0, int k1,
    floatx16& accC, floatx16& accH)
{
    const u16* ap  = ah + (size_t)(m0 + r31) * SP + seg;
    const u16* alp = al + (size_t)(m0 + r31) * SP + seg;
    const u16* wch = wh + (size_t)rc * SP + seg;
    const u16* wcl = wl + (size_t)rc * SP + seg;
    const u16* whh = wh + (size_t)rh * SP + seg;
    const u16* whl = wl + (size_t)rh * SP + seg;
#pragma unroll 2
    for (int kp = k0; kp < k1; kp += 16) {
        const short8 a_h = *(const short8*)(ap  + kp);
        const short8 a_l = *(const short8*)(alp + kp);
        const short8 bch = *(const short8*)(wch + kp);
        const short8 bcl = *(const short8*)(wcl + kp);
        const short8 bhh = *(const short8*)(whh + kp);
        const short8 bhl = *(const short8*)(whl + kp);
        accC = __builtin_amdgcn_mfma_f32_32x32x16_bf16(a_h, bch, accC, 0, 0, 0);
        accH = __builtin_amdgcn_mfma_f32_32x32x16_bf16(a_h, bhh, accH, 0, 0, 0);
        accC = __builtin_amdgcn_mfma_f32_32x32x16_bf16(a_l, bch, accC, 0, 0, 0);
        accH = __builtin_amdgcn_mfma_f32_32x32x16_bf16(a_l, bhh, accH, 0, 0, 0);
        accC = __builtin_amdgcn_mfma_f32_32x32x16_bf16(a_h, bcl, accC, 0, 0, 0);
        accH = __builtin_amdgcn_mfma_f32_32x32x16_bf16(a_h, bhl, accH, 0, 0, 0);
    }
}

// ---- K-loop over fp32 X with in-register split, ranged ----
__device__ __forceinline__ void kloop_x_rng(
    const float* __restrict__ X,
    const u16* __restrict__ wh, const u16* __restrict__ wl,
    int m0, int rc, int rh, int r31, int seg, int k0, int k1,
    floatx16& accC, floatx16& accH)
{
    const float* xr = X + (size_t)(m0 + r31) * H_;
    const u16* wch = wh + (size_t)rc * SP + seg;
    const u16* wcl = wl + (size_t)rc * SP + seg;
    const u16* whh = wh + (size_t)rh * SP + seg;
    const u16* whl = wl + (size_t)rh * SP + seg;
#pragma unroll 2
    for (int kp = k0; kp < k1; kp += 16) {
        const int c0 = kp + seg;
        float v[8];
        if (c0 + 8 <= H_) {
#pragma unroll
            for (int j = 0; j < 8; j += 2) {
                const float2 t2 = *(const float2*)(xr + c0 + j);  // 8B aligned
                v[j] = t2.x; v[j + 1] = t2.y;
            }
        } else {
#pragma unroll
            for (int j = 0; j < 8; j++) v[j] = (c0 + j < H_) ? xr[c0 + j] : 0.f;
        }
        short8 a_h, a_l;
#pragma unroll
        for (int j = 0; j < 8; j++) {
            u16 hi, lo; split2(v[j], hi, lo);
            a_h[j] = (short)hi;
            a_l[j] = (short)lo;
        }
        const short8 bch = *(const short8*)(wch + kp);
        const short8 bcl = *(const short8*)(wcl + kp);
        const short8 bhh = *(const short8*)(whh + kp);
        const short8 bhl = *(const short8*)(whl + kp);
        accC = __builtin_amdgcn_mfma_f32_32x32x16_bf16(a_h, bch, accC, 0, 0, 0);
        accH = __builtin_amdgcn_mfma_f32_32x32x16_bf16(a_h, bhh, accH, 0, 0, 0);
        accC = __builtin_amdgcn_mfma_f32_32x32x16_bf16(a_l, bch, accC, 0, 0, 0);
        accH = __builtin_amdgcn_mfma_f32_32x32x16_bf16(a_l, bhh, accH, 0, 0, 0);
        accC = __builtin_amdgcn_mfma_f32_32x32x16_bf16(a_h, bcl, accC, 0, 0, 0);
        accH = __builtin_amdgcn_mfma_f32_32x32x16_bf16(a_h, bhl, accH, 0, 0, 0);
    }
}

// ---- one-time big GEMM: XW[t*B+b][0..1700) = X[t,b,:] @ W0x  (64x64 block, 4 waves, full K) ----
// grid (14, 1, 512).  STAGED: read bf16 planes; else read fp32 X with in-register split.
template <bool STAGED>
__global__ __launch_bounds__(256, 2) void xw_gemm(
    const u16* __restrict__ WH, const u16* __restrict__ WL,
    const u16* __restrict__ XH, const u16* __restrict__ XL,
    const float* __restrict__ X, float* __restrict__ XW)
{
    const int lane = threadIdx.x & 63;
    const int wv   = threadIdx.x >> 6;
    const int m0 = blockIdx.z * 64 + (wv & 1) * 32;
    const int n0 = blockIdx.x * 64 + (wv >> 1) * 32;
    const int r31 = lane & 31;
    const int seg = (lane >> 5) << 3;
    const int colB = n0 + r31;               // <= 895
    const int rc = colB;
    const int rh = min(850 + colB, 1699);

    floatx16 accC, accH;
#pragma unroll
    for (int i = 0; i < 16; i++) { accC[i] = 0.f; accH[i] = 0.f; }

    if (STAGED)
        kloop_planes_rng(XH, XL, WH, WL, m0, rc, rh, r31, seg, 0, SP, accC, accH);
    else
        kloop_x_rng(X, WH, WL, m0, rc, rh, r31, seg, 0, SP, accC, accH);

    if (colB < H_) {
        const int rbase = m0 + ((lane >> 5) << 2);
#pragma unroll
        for (int r = 0; r < 16; r++) {
            const int row = rbase + (r & 3) + ((r >> 2) << 3);
            XW[(size_t)row * 1700 + colB]       = accC[r];
            XW[(size_t)row * 1700 + 850 + colB] = accH[r];
        }
    }
}

// ---- tall-tile fused GEMM + cell update ----
// block = 256 thr = 4 waves; BM=128: each wave owns one 32-row m-subtile, walks FULL K.
// All 4 waves read identical weight addresses in near-lockstep -> L1 serves 3 of 4.
// No LDS, no __syncthreads, epilogue straight from MFMA accs.
// MODE 0: stage1 main (h-plane K, + XW add in epilogue), XF = XW + t*B*1700
// MODE 1: node GEMM (grid.y selects node, base offset)
// MODE 2: stage1 fallback (x fp32 in-register split + h-plane, both full K), XF = X + t*BH
// grid (27, nodes, 2)
template <int MODE>
__global__ __launch_bounds__(256, 2) void gemm_wide(
    const u16* __restrict__ WH, const u16* __restrict__ WL,
    u16* __restrict__ SH, u16* __restrict__ SL,
    const float* __restrict__ XF, int base)
{
    const int lane = threadIdx.x & 63;
    const int wv   = threadIdx.x >> 6;
    const int m0 = blockIdx.z * 128 + wv * 32;
    const int n0 = blockIdx.x * 32;
    const int r31 = lane & 31;
    const int seg = (lane >> 5) << 3;
    const int colB = n0 + r31;               // < 864
    const int rc = colB;
    const int rh = min(850 + colB, 1699);

    int pred, act, outp, wi;
    if (MODE != 1) { pred = 9; act = 0; outp = 0; wi = 1; }
    else {
        const int node = base + blockIdx.y;
        pred = PRED[node]; act = ACTID[node];
        outp = node + 1; wi = 2 + node;
    }

    floatx16 accC, accH;
#pragma unroll
    for (int i = 0; i < 16; i++) { accC[i] = 0.f; accH[i] = 0.f; }

    if (MODE == 2) {
        kloop_x_rng(XF, WH, WL, m0, rc, rh, r31, seg, 0, SP, accC, accH);
        kloop_planes_rng(SH + 9 * (size_t)PS, SL + 9 * (size_t)PS,
                         WH + (size_t)WMS, WL + (size_t)WMS,
                         m0, rc, rh, r31, seg, 0, SP, accC, accH);
    } else {
        kloop_planes_rng(SH + (size_t)pred * PS, SL + (size_t)pred * PS,
                         WH + (size_t)wi * WMS, WL + (size_t)wi * WMS,
                         m0, rc, rh, r31, seg, 0, SP, accC, accH);
    }

    // epilogue: C/D layout col=lane&31, row=(reg&3)+8*(reg>>2)+4*(lane>>5)
    if (colB < H_) {
        const u16* ph = SH + (size_t)pred * PS;
        const u16* pl = SL + (size_t)pred * PS;
        u16* oh = SH + (size_t)outp * PS;
        u16* ol = SL + (size_t)outp * PS;
        const int rbase = m0 + ((lane >> 5) << 2);
#pragma unroll
        for (int r = 0; r < 16; r++) {
            const int row = rbase + (r & 3) + ((r >> 2) << 3);
            float c = accC[r];
            float h = accH[r];
            if (MODE == 0) {
                c += XF[(size_t)row * 1700 + colB];
                h += XF[(size_t)row * 1700 + 850 + colB];
            }
            const size_t off = (size_t)row * SP + colB;
            const float s  = b2f(ph[off]) + b2f(pl[off]);
            const float hv = actf(act, h);
            const float o  = s + sigf(c) * (hv - s);
            u16 hi, lo; split2(o, hi, lo);
            oh[off] = hi; ol[off] = lo;
        }
    }
}

// ---- finalize: h = mean(s1..s8), write plane 9 + fp32 output ----
__global__ __launch_bounds__(256) void finalize_kern(
    u16* __restrict__ SH, u16* __restrict__ SL,
    float* __restrict__ OUT, float* __restrict__ OUT2)
{
    const int idx = blockIdx.x * 256 + threadIdx.x;   // exactly BH
    const int row = idx / H_, col = idx % H_;
    const size_t off = (size_t)row * SP + col;
    float s = 0.f;
#pragma unroll
    for (int p = 1; p <= 8; p++)
        s += b2f(SH[(size_t)p * PS + off]) + b2f(SL[(size_t)p * PS + off]);
    s *= 0.125f;
    u16 hi, lo; split2(s, hi, lo);
    SH[9 * (size_t)PS + off] = hi;
    SL[9 * (size_t)PS + off] = lo;
    OUT[idx] = s;
    if (OUT2) OUT2[idx] = s;
}

extern "C" void kernel_launch(void* const* d_in, const int* in_sizes, int n_in,
                              void* d_out, int out_size, void* d_ws, size_t ws_size,
                              hipStream_t stream) {
    const float* X   = (const float*)d_in[0];  // [128, 256, 850]
    const float* HID = (const float*)d_in[1];  // [1, 256, 850]
    const float* W0  = (const float*)d_in[2];  // [1700, 1700]
    const float* WS  = (const float*)d_in[3];  // [8, 850, 1700]

    // workspace layout (u16 unless noted):
    //   WH[10*WMS] WL[10*WMS] SH[10*PS] SL[10*PS] then tier-dependent:
    //   tier A: XH[TB*SP] XL[TB*SP] XW(fp32)[TB*1700]   (~403.7 MB total)
    //   tier B: XW(fp32)[TB*1700]                        (~290.4 MB total)
    //   tier C: nothing extra                            (~67.6 MB total)
    u16* WH = (u16*)d_ws;
    u16* WL = WH + (size_t)10 * WMS;
    u16* SH = WL + (size_t)10 * WMS;
    u16* SL = SH + (size_t)10 * PS;
    u16* XH = SL + (size_t)10 * PS;
    u16* XL = XH + (size_t)TB * SP;

    const size_t base_b = ((size_t)2 * 10 * WMS + (size_t)2 * 10 * PS) * 2;
    const size_t xw_b   = (size_t)TB * 1700 * 4;
    const size_t stage_b = (size_t)2 * TB * SP * 2;
    const size_t needA = base_b + stage_b + xw_b;   // ~403.7 MB
    const size_t needB = base_b + xw_b;             // ~290.4 MB

    const int tier = (ws_size >= needA) ? 0 : (ws_size >= needB) ? 1 : 2;
    float* XW = (tier == 0) ? (float*)(XL + (size_t)TB * SP)
                            : (float*)(SL + (size_t)10 * PS);

    float* OUT = (float*)d_out;

    transpose_w<<<dim3(14, 27, 10), 256, 0, stream>>>(W0, WS, WH, WL);
    init_kern<<<PS / 256, 256, 0, stream>>>(HID, SH, SL);
    zpad_kern<<<126, 256, 0, stream>>>(SH, SL);
    if (tier == 0) {
        stage_x<<<4096, 256, 0, stream>>>(X, XH, XL);
        xw_gemm<true ><<<dim3(14, 1, 512), 256, 0, stream>>>(WH, WL, XH, XL, X, XW);
    } else if (tier == 1) {
        xw_gemm<false><<<dim3(14, 1, 512), 256, 0, stream>>>(WH, WL, XH, XL, X, XW);
    }

    for (int t = 0; t < T_; t++) {
        if (tier <= 1)
            gemm_wide<0><<<dim3(27, 1, 2), 256, 0, stream>>>(
                WH, WL, SH, SL, XW + (size_t)t * B_ * 1700, 0);
        else
            gemm_wide<2><<<dim3(27, 1, 2), 256, 0, stream>>>(
                WH, WL, SH, SL, X + (size_t)t * BH, 0);
        gemm_wide<1><<<dim3(27, 2, 2), 256, 0, stream>>>(WH, WL, SH, SL, nullptr, 0);
        gemm_wide<1><<<dim3(27, 4, 2), 256, 0, stream>>>(WH, WL, SH, SL, nullptr, 2);
        gemm_wide<1><<<dim3(27, 2, 2), 256, 0, stream>>>(WH, WL, SH, SL, nullptr, 6);
        finalize_kern<<<850, 256, 0, stream>>>(
            SH, SL, OUT + (size_t)t * BH,
            (t == T_ - 1) ? (OUT + (size_t)T_ * BH) : (float*)nullptr);
    }
}

// Round 4
// 16374.731 us; speedup vs baseline: 1.7406x; 1.7406x over previous
//
#include <hip/hip_runtime.h>
#include <hip/hip_bf16.h>

typedef unsigned short u16;
typedef unsigned int u32;
typedef __attribute__((ext_vector_type(8))) short short8;
typedef __attribute__((ext_vector_type(16))) float floatx16;

#define T_ 128
#define B_ 256
#define H_ 850
#define BH (B_ * H_)          // 217600
#define SP 864                // padded K / plane column stride
#define PS (B_ * SP)          // state plane elems (221184)
#define WMS (1700 * SP)       // one transposed weight matrix elems
#define TB (T_ * B_)          // 32768 rows of the hoisted X GEMM

// ARCH pairs: (0,0),(0,1),(1,2),(1,3),(2,0),(2,1),(3,2),(4,3)
__device__ __constant__ int PRED[8]  = {0, 0, 1, 1, 2, 2, 3, 4};
__device__ __constant__ int ACTID[8] = {0, 1, 2, 3, 0, 1, 2, 3};

__device__ __forceinline__ float sigf(float x) { return 1.f / (1.f + __expf(-x)); }
__device__ __forceinline__ float actf(int a, float x) {
    if (a == 0) { float e = __expf(2.f * x); return 1.f - 2.f / (e + 1.f); } // tanh
    if (a == 1) return x > 0.f ? x : 0.f;
    if (a == 2) return sigf(x);
    return x;
}
__device__ __forceinline__ float b2f(u16 u) {
    return __uint_as_float(((u32)u) << 16);   // exact bf16 -> f32
}
__device__ __forceinline__ void split2(float x, u16& hi, u16& lo) {
    __hip_bfloat16 h = __float2bfloat16(x);
    float hf = __bfloat162float(h);
    __hip_bfloat16 l = __float2bfloat16(x - hf);
    hi = reinterpret_cast<u16&>(h);
    lo = reinterpret_cast<u16&>(l);
}

// ---- transpose + split: 10 matrices, each src [850 k][1700 n] -> WT [1700 n][864 k] hi/lo ----
__global__ __launch_bounds__(256) void transpose_w(
    const float* __restrict__ W0, const float* __restrict__ WS,
    u16* __restrict__ WH, u16* __restrict__ WL)
{
    const int z = blockIdx.z;
    const float* src = (z == 0) ? W0 : (z == 1) ? (W0 + (size_t)850 * 1700)
                       : (WS + (size_t)(z - 2) * 850 * 1700);
    u16* dh = WH + (size_t)z * WMS;
    u16* dl = WL + (size_t)z * WMS;
    const int k0 = blockIdx.x * 64;
    const int n0 = blockIdx.y * 64;

    __shared__ float tile[64][65];
    const int t = threadIdx.x;
    const int cn = t & 63;
    const int rb = (t >> 6) * 16;
#pragma unroll
    for (int j = 0; j < 16; j++) {
        const int k = k0 + rb + j;
        const int n = n0 + cn;
        float v = 0.f;
        if (k < 850 && n < 1700) v = src[(size_t)k * 1700 + n];
        tile[rb + j][cn] = v;
    }
    __syncthreads();
    const int r  = t >> 2;
    const int c0 = (t & 3) * 16;
    const int n = n0 + r;
    if (n < 1700) {
#pragma unroll
        for (int j = 0; j < 16; j += 2) {
            const int kk = k0 + c0 + j;
            if (kk < SP) {
                u16 h0, l0, h1, l1;
                split2(tile[c0 + j][r],     h0, l0);
                split2(tile[c0 + j + 1][r], h1, l1);
                *(u32*)(dh + (size_t)n * SP + kk) = (u32)h0 | ((u32)h1 << 16);
                *(u32*)(dl + (size_t)n * SP + kk) = (u32)l0 | ((u32)l1 << 16);
            }
        }
    }
}

// ---- init: split fp32 hidden into plane 9 (hi/lo), zero pad cols ----
__global__ __launch_bounds__(256) void init_kern(
    const float* __restrict__ HID, u16* __restrict__ SH, u16* __restrict__ SL)
{
    const int idx = blockIdx.x * 256 + threadIdx.x;   // over PS
    const int row = idx / SP, col = idx % SP;
    float v = (col < H_) ? HID[row * H_ + col] : 0.f;
    u16 hi, lo; split2(v, hi, lo);
    SH[9 * PS + idx] = hi;
    SL[9 * PS + idx] = lo;
}

// ---- zero the pad columns of state planes 0..8 ----
__global__ __launch_bounds__(256) void zpad_kern(u16* __restrict__ SH, u16* __restrict__ SL)
{
    const int idx = blockIdx.x * 256 + threadIdx.x;   // 9*256*14 = 32256
    if (idx >= 9 * B_ * 14) return;
    const int p = idx / (B_ * 14);
    const int rem = idx % (B_ * 14);
    const int row = rem / 14;
    const int c = H_ + rem % 14;
    const size_t off = (size_t)p * PS + row * SP + c;
    SH[off] = 0; SL[off] = 0;
}

// ---- stage X as bf16 hi/lo planes [TB rows][SP cols] (tier A only) ----
__global__ __launch_bounds__(256) void stage_x(
    const float* __restrict__ X, u16* __restrict__ XH, u16* __restrict__ XL)
{
    const int total = TB * SP;
    for (int idx = blockIdx.x * 256 + threadIdx.x; idx < total; idx += gridDim.x * 256) {
        const int row = idx / SP;
        const int col = idx - row * SP;
        float v = (col < H_) ? X[(size_t)row * H_ + col] : 0.f;
        u16 hi, lo; split2(v, hi, lo);
        XH[idx] = hi; XL[idx] = lo;
    }
}

// ---- K-loop over bf16 hi/lo planes, ranged [k0,k1) ----
__device__ __forceinline__ void kloop_planes_rng(
    const u16* __restrict__ ah, const u16* __restrict__ al,
    const u16* __restrict__ wh, const u16* __restrict__ wl,
    int m0, int rc, int rh, int r31, int seg, int k0, int k1,
    floatx16& accC, floatx16& accH)
{
    const u16* ap  = ah + (size_t)(m0 + r31) * SP + seg;
    const u16* alp = al + (size_t)(m0 + r31) * SP + seg;
    const u16* wch = wh + (size_t)rc * SP + seg;
    const u16* wcl = wl + (size_t)rc * SP + seg;
    const u16* whh = wh + (size_t)rh * SP + seg;
    const u16* whl = wl + (size_t)rh * SP + seg;
#pragma unroll 2
    for (int kp = k0; kp < k1; kp += 16) {
        const short8 a_h = *(const short8*)(ap  + kp);
        const short8 a_l = *(const short8*)(alp + kp);
        const short8 bch = *(const short8*)(wch + kp);
        const short8 bcl = *(const short8*)(wcl + kp);
        const short8 bhh = *(const short8*)(whh + kp);
        const short8 bhl = *(const short8*)(whl + kp);
        accC = __builtin_amdgcn_mfma_f32_32x32x16_bf16(a_h, bch, accC, 0, 0, 0);
        accH = __builtin_amdgcn_mfma_f32_32x32x16_bf16(a_h, bhh, accH, 0, 0, 0);
        accC = __builtin_amdgcn_mfma_f32_32x32x16_bf16(a_l, bch, accC, 0, 0, 0);
        accH = __builtin_amdgcn_mfma_f32_32x32x16_bf16(a_l, bhh, accH, 0, 0, 0);
        accC = __builtin_amdgcn_mfma_f32_32x32x16_bf16(a_h, bcl, accC, 0, 0, 0);
        accH = __builtin_amdgcn_mfma_f32_32x32x16_bf16(a_h, bhl, accH, 0, 0, 0);
    }
}

// ---- K-loop over fp32 X with in-register split, ranged ----
__device__ __forceinline__ void kloop_x_rng(
    const float* __restrict__ X,
    const u16* __restrict__ wh, const u16* __restrict__ wl,
    int m0, int rc, int rh, int r31, int seg, int k0, int k1,
    floatx16& accC, floatx16& accH)
{
    const float* xr = X + (size_t)(m0 + r31) * H_;
    const u16* wch = wh + (size_t)rc * SP + seg;
    const u16* wcl = wl + (size_t)rc * SP + seg;
    const u16* whh = wh + (size_t)rh * SP + seg;
    const u16* whl = wl + (size_t)rh * SP + seg;
#pragma unroll 2
    for (int kp = k0; kp < k1; kp += 16) {
        const int c0 = kp + seg;
        float v[8];
        if (c0 + 8 <= H_) {
#pragma unroll
            for (int j = 0; j < 8; j += 2) {
                const float2 t2 = *(const float2*)(xr + c0 + j);
                v[j] = t2.x; v[j + 1] = t2.y;
            }
        } else {
#pragma unroll
            for (int j = 0; j < 8; j++) v[j] = (c0 + j < H_) ? xr[c0 + j] : 0.f;
        }
        short8 a_h, a_l;
#pragma unroll
        for (int j = 0; j < 8; j++) {
            u16 hi, lo; split2(v[j], hi, lo);
            a_h[j] = (short)hi;
            a_l[j] = (short)lo;
        }
        const short8 bch = *(const short8*)(wch + kp);
        const short8 bcl = *(const short8*)(wcl + kp);
        const short8 bhh = *(const short8*)(whh + kp);
        const short8 bhl = *(const short8*)(whl + kp);
        accC = __builtin_amdgcn_mfma_f32_32x32x16_bf16(a_h, bch, accC, 0, 0, 0);
        accH = __builtin_amdgcn_mfma_f32_32x32x16_bf16(a_h, bhh, accH, 0, 0, 0);
        accC = __builtin_amdgcn_mfma_f32_32x32x16_bf16(a_l, bch, accC, 0, 0, 0);
        accH = __builtin_amdgcn_mfma_f32_32x32x16_bf16(a_l, bhh, accH, 0, 0, 0);
        accC = __builtin_amdgcn_mfma_f32_32x32x16_bf16(a_h, bcl, accC, 0, 0, 0);
        accH = __builtin_amdgcn_mfma_f32_32x32x16_bf16(a_h, bhl, accH, 0, 0, 0);
    }
}

// ---- one-time big GEMM: XW = X @ W0x, grid (14, 1, 512), 4 waves x 32x32 tiles ----
template <bool STAGED>
__global__ __launch_bounds__(256, 2) void xw_gemm(
    const u16* __restrict__ WH, const u16* __restrict__ WL,
    const u16* __restrict__ XH, const u16* __restrict__ XL,
    const float* __restrict__ X, float* __restrict__ XW)
{
    const int lane = threadIdx.x & 63;
    const int wv   = threadIdx.x >> 6;
    const int m0 = blockIdx.z * 64 + (wv & 1) * 32;
    const int n0 = blockIdx.x * 64 + (wv >> 1) * 32;
    const int r31 = lane & 31;
    const int seg = (lane >> 5) << 3;
    const int colB = n0 + r31;
    const int rc = colB;
    const int rh = min(850 + colB, 1699);

    floatx16 accC, accH;
#pragma unroll
    for (int i = 0; i < 16; i++) { accC[i] = 0.f; accH[i] = 0.f; }

    if (STAGED)
        kloop_planes_rng(XH, XL, WH, WL, m0, rc, rh, r31, seg, 0, SP, accC, accH);
    else
        kloop_x_rng(X, WH, WL, m0, rc, rh, r31, seg, 0, SP, accC, accH);

    if (colB < H_) {
        const int rbase = m0 + ((lane >> 5) << 2);
#pragma unroll
        for (int r = 0; r < 16; r++) {
            const int row = rbase + (r & 3) + ((r >> 2) << 3);
            XW[(size_t)row * 1700 + colB]       = accC[r];
            XW[(size_t)row * 1700 + 850 + colB] = accH[r];
        }
    }
}

// ---- 8-way split-K fused GEMM + cell update ----
// block = 512 thr = 8 waves; one 32x32 output tile per block; each wave owns a 112-wide
// K-chunk (wave 7: 80). LDS 8-partial reduction, fused cell-update epilogue (paired u32).
// grid (32 [n, padded so linear_id%8 == n%8 -> XCD-aligned B slices], nodes, 8 [m]).
// MODE 0: stage1 main (h-plane K + XW add), XF = XW + t*B*1700
// MODE 1: node GEMM; MODE 2: stage1 fallback (waves 0-3 x fp32, waves 4-7 h-plane)
template <int MODE>
__global__ __launch_bounds__(512, 4) void gemm_fat(
    const u16* __restrict__ WH, const u16* __restrict__ WL,
    u16* __restrict__ SH, u16* __restrict__ SL,
    const float* __restrict__ XF, int base)
{
    if (blockIdx.x >= 27) return;           // n-grid padded to 32 for XCD alignment
    const int lane = threadIdx.x & 63;
    const int wv   = threadIdx.x >> 6;      // 0..7 = K-chunk id
    const int m0 = blockIdx.z * 32;
    const int n0 = blockIdx.x * 32;
    const int r31 = lane & 31;
    const int seg = (lane >> 5) << 3;
    const int colB = n0 + r31;              // < 864
    const int rc = colB;
    const int rh = min(850 + colB, 1699);

    int pred, act, outp, wi;
    if (MODE != 1) { pred = 9; act = 0; outp = 0; wi = 1; }
    else {
        const int node = base + blockIdx.y;
        pred = PRED[node]; act = ACTID[node];
        outp = node + 1; wi = 2 + node;
    }

    floatx16 accC, accH;
#pragma unroll
    for (int i = 0; i < 16; i++) { accC[i] = 0.f; accH[i] = 0.f; }

    if (MODE == 2) {
        // waves 0-3: x-part (fp32 in-register split), waves 4-7: h-plane
        if (wv < 4) {
            const int k0 = wv * 224;
            kloop_x_rng(XF, WH, WL, m0, rc, rh, r31, seg,
                        k0, min(SP, k0 + 224), accC, accH);
        } else {
            const int k0 = (wv - 4) * 224;
            kloop_planes_rng(SH + 9 * (size_t)PS, SL + 9 * (size_t)PS,
                             WH + (size_t)WMS, WL + (size_t)WMS,
                             m0, rc, rh, r31, seg, k0, min(SP, k0 + 224), accC, accH);
        }
    } else {
        const int k0 = wv * 112;
        const int k1 = min(SP, k0 + 112);   // wave 7: 784..864
        kloop_planes_rng(SH + (size_t)pred * PS, SL + (size_t)pred * PS,
                         WH + (size_t)wi * WMS, WL + (size_t)wi * WMS,
                         m0, rc, rh, r31, seg, k0, k1, accC, accH);
    }

    // 8-partial LDS reduction (64 KB)
    __shared__ float redC[8][1024];
    __shared__ float redH[8][1024];
    {
        const int rb = (lane >> 5) << 2;
#pragma unroll
        for (int r = 0; r < 16; r++) {
            const int row = rb + (r & 3) + ((r >> 2) << 3);
            redC[wv][row * 32 + r31] = accC[r];
            redH[wv][row * 32 + r31] = accH[r];
        }
    }
    __syncthreads();

    // epilogue: 512 threads x 2 adjacent cols (paired u32/float2 access)
    const int e = threadIdx.x * 2;          // 0..1022
    const int row = e >> 5;
    const int gcol = n0 + (e & 31);         // even; H_ even -> pair fully valid or not
    if (gcol < H_) {
        float cA = 0.f, cB = 0.f, hA = 0.f, hB = 0.f;
#pragma unroll
        for (int w = 0; w < 8; w++) {
            cA += redC[w][e]; cB += redC[w][e + 1];
            hA += redH[w][e]; hB += redH[w][e + 1];
        }
        const int grow = m0 + row;
        if (MODE == 0) {
            const float2 xc = *(const float2*)(XF + (size_t)grow * 1700 + gcol);
            const float2 xh = *(const float2*)(XF + (size_t)grow * 1700 + 850 + gcol);
            cA += xc.x; cB += xc.y; hA += xh.x; hB += xh.y;
        }
        const size_t off = (size_t)grow * SP + gcol;
        const u32 phv = *(const u32*)(SH + (size_t)pred * PS + off);
        const u32 plv = *(const u32*)(SL + (size_t)pred * PS + off);
        const float sA = b2f((u16)(phv & 0xffff)) + b2f((u16)(plv & 0xffff));
        const float sB = b2f((u16)(phv >> 16))    + b2f((u16)(plv >> 16));
        const float oA = sA + sigf(cA) * (actf(act, hA) - sA);
        const float oB = sB + sigf(cB) * (actf(act, hB) - sB);
        u16 hiA, loA, hiB, loB;
        split2(oA, hiA, loA); split2(oB, hiB, loB);
        *(u32*)(SH + (size_t)outp * PS + off) = (u32)hiA | ((u32)hiB << 16);
        *(u32*)(SL + (size_t)outp * PS + off) = (u32)loA | ((u32)loB << 16);
    }
}

// ---- finalize: h = mean(s1..s8), write plane 9 + fp32 output (paired u32/float2) ----
__global__ __launch_bounds__(256) void finalize_kern(
    u16* __restrict__ SH, u16* __restrict__ SL,
    float* __restrict__ OUT, float* __restrict__ OUT2)
{
    const int idx = blockIdx.x * 256 + threadIdx.x;   // 425*256 = 108800 = BH/2
    const int row = idx / 425;
    const int col = (idx - row * 425) * 2;
    const size_t off = (size_t)row * SP + col;
    float sA = 0.f, sB = 0.f;
#pragma unroll
    for (int p = 1; p <= 8; p++) {
        const u32 hv = *(const u32*)(SH + (size_t)p * PS + off);
        const u32 lv = *(const u32*)(SL + (size_t)p * PS + off);
        sA += b2f((u16)(hv & 0xffff)) + b2f((u16)(lv & 0xffff));
        sB += b2f((u16)(hv >> 16))    + b2f((u16)(lv >> 16));
    }
    sA *= 0.125f; sB *= 0.125f;
    u16 hiA, loA, hiB, loB;
    split2(sA, hiA, loA); split2(sB, hiB, loB);
    *(u32*)(SH + 9 * (size_t)PS + off) = (u32)hiA | ((u32)hiB << 16);
    *(u32*)(SL + 9 * (size_t)PS + off) = (u32)loA | ((u32)loB << 16);
    const int oidx = row * H_ + col;
    *(float2*)(OUT + oidx) = make_float2(sA, sB);
    if (OUT2) *(float2*)(OUT2 + oidx) = make_float2(sA, sB);
}

extern "C" void kernel_launch(void* const* d_in, const int* in_sizes, int n_in,
                              void* d_out, int out_size, void* d_ws, size_t ws_size,
                              hipStream_t stream) {
    const float* X   = (const float*)d_in[0];  // [128, 256, 850]
    const float* HID = (const float*)d_in[1];  // [1, 256, 850]
    const float* W0  = (const float*)d_in[2];  // [1700, 1700]
    const float* WS  = (const float*)d_in[3];  // [8, 850, 1700]

    u16* WH = (u16*)d_ws;
    u16* WL = WH + (size_t)10 * WMS;
    u16* SH = WL + (size_t)10 * WMS;
    u16* SL = SH + (size_t)10 * PS;
    u16* XH = SL + (size_t)10 * PS;
    u16* XL = XH + (size_t)TB * SP;

    const size_t base_b = ((size_t)2 * 10 * WMS + (size_t)2 * 10 * PS) * 2;
    const size_t xw_b   = (size_t)TB * 1700 * 4;
    const size_t stage_b = (size_t)2 * TB * SP * 2;
    const size_t needA = base_b + stage_b + xw_b;   // ~403.7 MB
    const size_t needB = base_b + xw_b;             // ~290.4 MB

    const int tier = (ws_size >= needA) ? 0 : (ws_size >= needB) ? 1 : 2;
    float* XW = (tier == 0) ? (float*)(XL + (size_t)TB * SP)
                            : (float*)(SL + (size_t)10 * PS);

    float* OUT = (float*)d_out;

    transpose_w<<<dim3(14, 27, 10), 256, 0, stream>>>(W0, WS, WH, WL);
    init_kern<<<PS / 256, 256, 0, stream>>>(HID, SH, SL);
    zpad_kern<<<126, 256, 0, stream>>>(SH, SL);
    if (tier == 0) {
        stage_x<<<4096, 256, 0, stream>>>(X, XH, XL);
        xw_gemm<true ><<<dim3(14, 1, 512), 256, 0, stream>>>(WH, WL, XH, XL, X, XW);
    } else if (tier == 1) {
        xw_gemm<false><<<dim3(14, 1, 512), 256, 0, stream>>>(WH, WL, XH, XL, X, XW);
    }

    for (int t = 0; t < T_; t++) {
        if (tier <= 1)
            gemm_fat<0><<<dim3(32, 1, 8), 512, 0, stream>>>(
                WH, WL, SH, SL, XW + (size_t)t * B_ * 1700, 0);
        else
            gemm_fat<2><<<dim3(32, 1, 8), 512, 0, stream>>>(
                WH, WL, SH, SL, X + (size_t)t * BH, 0);
        gemm_fat<1><<<dim3(32, 2, 8), 512, 0, stream>>>(WH, WL, SH, SL, nullptr, 0);
        gemm_fat<1><<<dim3(32, 4, 8), 512, 0, stream>>>(WH, WL, SH, SL, nullptr, 2);
        gemm_fat<1><<<dim3(32, 2, 8), 512, 0, stream>>>(WH, WL, SH, SL, nullptr, 6);
        finalize_kern<<<425, 256, 0, stream>>>(
            SH, SL, OUT + (size_t)t * BH,
            (t == T_ - 1) ? (OUT + (size_t)T_ * BH) : (float*)nullptr);
    }
}

// Round 5
// 8350.489 us; speedup vs baseline: 3.4132x; 1.9609x over previous
//
#include <hip/hip_runtime.h>
#include <hip/hip_bf16.h>

typedef unsigned short u16;
typedef unsigned int u32;
typedef __attribute__((ext_vector_type(8))) short short8;
typedef __attribute__((ext_vector_type(16))) float floatx16;

#define T_ 128
#define B_ 256
#define H_ 850
#define BH (B_ * H_)          // 217600
#define SP 864                // padded K (54 ksteps of 16)
#define NKS 54                // SP/16
#define PS (B_ * SP)          // state plane elems (221184) ; layout [54][256][16]
#define WMS (1700 * SP)       // one weight matrix elems    ; layout [54][1700][16]
#define WKS (1700 * 16)       // 27200: W kstep stride (u16)
#define TB (T_ * B_)          // 32768 rows of the hoisted X GEMM
#define XKS (TB * 16)         // 524288 = 2^19: X kstep stride (u16)

// ARCH pairs: (0,0),(0,1),(1,2),(1,3),(2,0),(2,1),(3,2),(4,3)
__device__ __constant__ int PRED[8]  = {0, 0, 1, 1, 2, 2, 3, 4};
__device__ __constant__ int ACTID[8] = {0, 1, 2, 3, 0, 1, 2, 3};

__device__ __forceinline__ float sigf(float x) { return 1.f / (1.f + __expf(-x)); }
__device__ __forceinline__ float actf(int a, float x) {
    if (a == 0) { float e = __expf(2.f * x); return 1.f - 2.f / (e + 1.f); } // tanh
    if (a == 1) return x > 0.f ? x : 0.f;
    if (a == 2) return sigf(x);
    return x;
}
__device__ __forceinline__ float b2f(u16 u) {
    return __uint_as_float(((u32)u) << 16);   // exact bf16 -> f32
}
__device__ __forceinline__ void split2(float x, u16& hi, u16& lo) {
    __hip_bfloat16 h = __float2bfloat16(x);
    float hf = __bfloat162float(h);
    __hip_bfloat16 l = __float2bfloat16(x - hf);
    hi = reinterpret_cast<u16&>(h);
    lo = reinterpret_cast<u16&>(l);
}

// ---- transpose + split: 10 matrices, src [850 k][1700 n] -> WT [54 ks][1700 n][16 kin] hi/lo ----
__global__ __launch_bounds__(256) void transpose_w(
    const float* __restrict__ W0, const float* __restrict__ WS,
    u16* __restrict__ WH, u16* __restrict__ WL)
{
    const int z = blockIdx.z;
    const float* src = (z == 0) ? W0 : (z == 1) ? (W0 + (size_t)850 * 1700)
                       : (WS + (size_t)(z - 2) * 850 * 1700);
    u16* dh = WH + (size_t)z * WMS;
    u16* dl = WL + (size_t)z * WMS;
    const int k0 = blockIdx.x * 64;
    const int n0 = blockIdx.y * 64;

    __shared__ float tile[64][65];
    const int t = threadIdx.x;
    const int cn = t & 63;
    const int rb = (t >> 6) * 16;
#pragma unroll
    for (int j = 0; j < 16; j++) {
        const int k = k0 + rb + j;
        const int n = n0 + cn;
        float v = 0.f;
        if (k < 850 && n < 1700) v = src[(size_t)k * 1700 + n];
        tile[rb + j][cn] = v;
    }
    __syncthreads();
    const int r  = t >> 2;
    const int c0 = (t & 3) * 16;
    const int n = n0 + r;
    if (n < 1700) {
#pragma unroll
        for (int j = 0; j < 16; j += 2) {
            const int kk = k0 + c0 + j;
            if (kk < SP) {
                u16 h0, l0, h1, l1;
                split2(tile[c0 + j][r],     h0, l0);
                split2(tile[c0 + j + 1][r], h1, l1);
                const size_t o = (size_t)(kk >> 4) * WKS + (size_t)n * 16 + (kk & 15);
                *(u32*)(dh + o) = (u32)h0 | ((u32)h1 << 16);
                *(u32*)(dl + o) = (u32)l0 | ((u32)l1 << 16);
            }
        }
    }
}

// ---- init: split fp32 hidden into plane 9 (incl. zero pad), layout [54][256][16] ----
__global__ __launch_bounds__(256) void init_kern(
    const float* __restrict__ HID, u16* __restrict__ SH, u16* __restrict__ SL)
{
    const int idx = blockIdx.x * 256 + threadIdx.x;   // over PS; addr == idx
    const int ks  = idx >> 12;          // /4096
    const int row = (idx >> 4) & 255;
    const int col = ks * 16 + (idx & 15);
    float v = (col < H_) ? HID[row * H_ + col] : 0.f;
    u16 hi, lo; split2(v, hi, lo);
    SH[9 * PS + idx] = hi;
    SL[9 * PS + idx] = lo;
}

// ---- zero the pad region (ks=53, kin=2..15) of state planes 0..8 ----
__global__ __launch_bounds__(256) void zpad_kern(u16* __restrict__ SH, u16* __restrict__ SL)
{
    const int idx = blockIdx.x * 256 + threadIdx.x;   // 9*256*14 = 32256
    if (idx >= 9 * B_ * 14) return;
    const int p = idx / (B_ * 14);
    const int rem = idx % (B_ * 14);
    const int row = rem / 14;
    const int c = 2 + rem % 14;                       // kin 2..15
    const size_t off = (size_t)p * PS + 53 * 4096 + row * 16 + c;
    SH[off] = 0; SL[off] = 0;
}

// ---- stage X as bf16 hi/lo planes, layout [54][32768][16] (tier A only) ----
__global__ __launch_bounds__(256) void stage_x(
    const float* __restrict__ X, u16* __restrict__ XH, u16* __restrict__ XL)
{
    const int total = TB * SP;
    for (int idx = blockIdx.x * 256 + threadIdx.x; idx < total; idx += gridDim.x * 256) {
        const int ks  = idx >> 19;          // /XKS
        const int row = (idx >> 4) & (TB - 1);
        const int col = ks * 16 + (idx & 15);
        float v = (col < H_) ? X[(size_t)row * H_ + col] : 0.f;
        u16 hi, lo; split2(v, hi, lo);
        XH[idx] = hi; XL[idx] = lo;
    }
}

// ---- K-loop over fragment-native bf16 hi/lo planes, ranged [k0,k1), arows = A row count ----
// A frag load: 16 contiguous u16 per lane, wave covers 1 KB dense burst. Same for W.
__device__ __forceinline__ void kloop_planes_rng(
    const u16* __restrict__ ah, const u16* __restrict__ al,
    const u16* __restrict__ wh, const u16* __restrict__ wl,
    int m0, int rc, int rh, int r31, int seg, int k0, int k1, int arows,
    floatx16& accC, floatx16& accH)
{
    const size_t AS = (size_t)arows * 16;
    const size_t abase = (size_t)(m0 + r31) * 16 + seg;
    const u16* ap  = ah + abase + (size_t)(k0 >> 4) * AS;
    const u16* alp = al + abase + (size_t)(k0 >> 4) * AS;
    const size_t wcb = (size_t)rc * 16 + seg + (size_t)(k0 >> 4) * WKS;
    const size_t whb = (size_t)rh * 16 + seg + (size_t)(k0 >> 4) * WKS;
    const u16* wch = wh + wcb;
    const u16* wcl = wl + wcb;
    const u16* whh = wh + whb;
    const u16* whl = wl + whb;
    const int nks = (k1 - k0) >> 4;
#pragma unroll 2
    for (int i = 0; i < nks; i++) {
        const short8 a_h = *(const short8*)ap;
        const short8 a_l = *(const short8*)alp;
        const short8 bch = *(const short8*)wch;
        const short8 bcl = *(const short8*)wcl;
        const short8 bhh = *(const short8*)whh;
        const short8 bhl = *(const short8*)whl;
        ap += AS; alp += AS;
        wch += WKS; wcl += WKS; whh += WKS; whl += WKS;
        accC = __builtin_amdgcn_mfma_f32_32x32x16_bf16(a_h, bch, accC, 0, 0, 0);
        accH = __builtin_amdgcn_mfma_f32_32x32x16_bf16(a_h, bhh, accH, 0, 0, 0);
        accC = __builtin_amdgcn_mfma_f32_32x32x16_bf16(a_l, bch, accC, 0, 0, 0);
        accH = __builtin_amdgcn_mfma_f32_32x32x16_bf16(a_l, bhh, accH, 0, 0, 0);
        accC = __builtin_amdgcn_mfma_f32_32x32x16_bf16(a_h, bcl, accC, 0, 0, 0);
        accH = __builtin_amdgcn_mfma_f32_32x32x16_bf16(a_h, bhl, accH, 0, 0, 0);
    }
}

// ---- K-loop over fp32 X (row-major input) with in-register split, ranged (tier B/C) ----
__device__ __forceinline__ void kloop_x_rng(
    const float* __restrict__ X,
    const u16* __restrict__ wh, const u16* __restrict__ wl,
    int m0, int rc, int rh, int r31, int seg, int k0, int k1,
    floatx16& accC, floatx16& accH)
{
    const float* xr = X + (size_t)(m0 + r31) * H_;
    const size_t wcb = (size_t)rc * 16 + seg + (size_t)(k0 >> 4) * WKS;
    const size_t whb = (size_t)rh * 16 + seg + (size_t)(k0 >> 4) * WKS;
    const u16* wch = wh + wcb;
    const u16* wcl = wl + wcb;
    const u16* whh = wh + whb;
    const u16* whl = wl + whb;
#pragma unroll 2
    for (int kp = k0; kp < k1; kp += 16) {
        const int c0 = kp + seg;
        float v[8];
        if (c0 + 8 <= H_) {
#pragma unroll
            for (int j = 0; j < 8; j += 2) {
                const float2 t2 = *(const float2*)(xr + c0 + j);
                v[j] = t2.x; v[j + 1] = t2.y;
            }
        } else {
#pragma unroll
            for (int j = 0; j < 8; j++) v[j] = (c0 + j < H_) ? xr[c0 + j] : 0.f;
        }
        short8 a_h, a_l;
#pragma unroll
        for (int j = 0; j < 8; j++) {
            u16 hi, lo; split2(v[j], hi, lo);
            a_h[j] = (short)hi;
            a_l[j] = (short)lo;
        }
        const short8 bch = *(const short8*)wch;
        const short8 bcl = *(const short8*)wcl;
        const short8 bhh = *(const short8*)whh;
        const short8 bhl = *(const short8*)whl;
        wch += WKS; wcl += WKS; whh += WKS; whl += WKS;
        accC = __builtin_amdgcn_mfma_f32_32x32x16_bf16(a_h, bch, accC, 0, 0, 0);
        accH = __builtin_amdgcn_mfma_f32_32x32x16_bf16(a_h, bhh, accH, 0, 0, 0);
        accC = __builtin_amdgcn_mfma_f32_32x32x16_bf16(a_l, bch, accC, 0, 0, 0);
        accH = __builtin_amdgcn_mfma_f32_32x32x16_bf16(a_l, bhh, accH, 0, 0, 0);
        accC = __builtin_amdgcn_mfma_f32_32x32x16_bf16(a_h, bcl, accC, 0, 0, 0);
        accH = __builtin_amdgcn_mfma_f32_32x32x16_bf16(a_h, bhl, accH, 0, 0, 0);
    }
}

// ---- one-time big GEMM: XW = X @ W0x, grid (14, 1, 512), 4 waves x 32x32 tiles ----
template <bool STAGED>
__global__ __launch_bounds__(256, 2) void xw_gemm(
    const u16* __restrict__ WH, const u16* __restrict__ WL,
    const u16* __restrict__ XH, const u16* __restrict__ XL,
    const float* __restrict__ X, float* __restrict__ XW)
{
    const int lane = threadIdx.x & 63;
    const int wv   = threadIdx.x >> 6;
    const int m0 = blockIdx.z * 64 + (wv & 1) * 32;
    const int n0 = blockIdx.x * 64 + (wv >> 1) * 32;
    const int r31 = lane & 31;
    const int seg = (lane >> 5) << 3;
    const int colB = n0 + r31;
    const int rc = colB;
    const int rh = min(850 + colB, 1699);

    floatx16 accC, accH;
#pragma unroll
    for (int i = 0; i < 16; i++) { accC[i] = 0.f; accH[i] = 0.f; }

    if (STAGED)
        kloop_planes_rng(XH, XL, WH, WL, m0, rc, rh, r31, seg, 0, SP, TB, accC, accH);
    else
        kloop_x_rng(X, WH, WL, m0, rc, rh, r31, seg, 0, SP, accC, accH);

    if (colB < H_) {
        const int rbase = m0 + ((lane >> 5) << 2);
#pragma unroll
        for (int r = 0; r < 16; r++) {
            const int row = rbase + (r & 3) + ((r >> 2) << 3);
            XW[(size_t)row * 1700 + colB]       = accC[r];
            XW[(size_t)row * 1700 + 850 + colB] = accH[r];
        }
    }
}

// ---- 8-way split-K fused GEMM + cell update ----
// block = 512 thr = 8 waves; one 32x32 output tile; waves = K-chunks; LDS reduce.
// grid (32 [n, padded: linear%8 == n%8 -> XCD-aligned], nodes, 8 [m]).
template <int MODE>
__global__ __launch_bounds__(512, 4) void gemm_fat(
    const u16* __restrict__ WH, const u16* __restrict__ WL,
    u16* __restrict__ SH, u16* __restrict__ SL,
    const float* __restrict__ XF, int base)
{
    if (blockIdx.x >= 27) return;
    const int lane = threadIdx.x & 63;
    const int wv   = threadIdx.x >> 6;      // 0..7 = K-chunk id
    const int m0 = blockIdx.z * 32;
    const int n0 = blockIdx.x * 32;
    const int r31 = lane & 31;
    const int seg = (lane >> 5) << 3;
    const int colB = n0 + r31;              // < 864
    const int rc = colB;
    const int rh = min(850 + colB, 1699);

    int pred, act, outp, wi;
    if (MODE != 1) { pred = 9; act = 0; outp = 0; wi = 1; }
    else {
        const int node = base + blockIdx.y;
        pred = PRED[node]; act = ACTID[node];
        outp = node + 1; wi = 2 + node;
    }

    floatx16 accC, accH;
#pragma unroll
    for (int i = 0; i < 16; i++) { accC[i] = 0.f; accH[i] = 0.f; }

    if (MODE == 2) {
        if (wv < 4) {
            const int k0 = wv * 224;
            kloop_x_rng(XF, WH, WL, m0, rc, rh, r31, seg,
                        k0, min(SP, k0 + 224), accC, accH);
        } else {
            const int k0 = (wv - 4) * 224;
            kloop_planes_rng(SH + 9 * (size_t)PS, SL + 9 * (size_t)PS,
                             WH + (size_t)WMS, WL + (size_t)WMS,
                             m0, rc, rh, r31, seg, k0, min(SP, k0 + 224), B_, accC, accH);
        }
    } else {
        const int k0 = wv * 112;
        const int k1 = min(SP, k0 + 112);
        kloop_planes_rng(SH + (size_t)pred * PS, SL + (size_t)pred * PS,
                         WH + (size_t)wi * WMS, WL + (size_t)wi * WMS,
                         m0, rc, rh, r31, seg, k0, k1, B_, accC, accH);
    }

    // 8-partial LDS reduction (64 KB)
    __shared__ float redC[8][1024];
    __shared__ float redH[8][1024];
    {
        const int rb = (lane >> 5) << 2;
#pragma unroll
        for (int r = 0; r < 16; r++) {
            const int row = rb + (r & 3) + ((r >> 2) << 3);
            redC[wv][row * 32 + r31] = accC[r];
            redH[wv][row * 32 + r31] = accH[r];
        }
    }
    __syncthreads();

    // epilogue: thread -> (row, even col pair) chosen so state u32 accesses are contiguous
    const int tt = threadIdx.x;
    const int colr = ((tt >> 8) << 4) + ((tt & 7) << 1);   // 0..30, even
    const int row  = (tt >> 3) & 31;
    const int gcol = n0 + colr;
    if (gcol < H_) {
        const int e = row * 32 + colr;
        float cA = 0.f, cB = 0.f, hA = 0.f, hB = 0.f;
#pragma unroll
        for (int w = 0; w < 8; w++) {
            cA += redC[w][e]; cB += redC[w][e + 1];
            hA += redH[w][e]; hB += redH[w][e + 1];
        }
        const int grow = m0 + row;
        if (MODE == 0) {
            const float2 xc = *(const float2*)(XF + (size_t)grow * 1700 + gcol);
            const float2 xh = *(const float2*)(XF + (size_t)grow * 1700 + 850 + gcol);
            cA += xc.x; cB += xc.y; hA += xh.x; hB += xh.y;
        }
        const size_t off = (size_t)(gcol >> 4) * 4096 + (size_t)grow * 16 + (gcol & 15);
        const u32 phv = *(const u32*)(SH + (size_t)pred * PS + off);
        const u32 plv = *(const u32*)(SL + (size_t)pred * PS + off);
        const float sA = b2f((u16)(phv & 0xffff)) + b2f((u16)(plv & 0xffff));
        const float sB = b2f((u16)(phv >> 16))    + b2f((u16)(plv >> 16));
        const float oA = sA + sigf(cA) * (actf(act, hA) - sA);
        const float oB = sB + sigf(cB) * (actf(act, hB) - sB);
        u16 hiA, loA, hiB, loB;
        split2(oA, hiA, loA); split2(oB, hiB, loB);
        *(u32*)(SH + (size_t)outp * PS + off) = (u32)hiA | ((u32)hiB << 16);
        *(u32*)(SL + (size_t)outp * PS + off) = (u32)loA | ((u32)loB << 16);
    }
}

// ---- finalize: h = mean(s1..s8), write plane 9 + fp32 output ----
__global__ __launch_bounds__(256) void finalize_kern(
    u16* __restrict__ SH, u16* __restrict__ SL,
    float* __restrict__ OUT, float* __restrict__ OUT2)
{
    const int idx = blockIdx.x * 256 + threadIdx.x;   // 425*256 = BH/2
    const int row = idx / 425;
    const int col = (idx - row * 425) * 2;            // 0..848 even, pair within kin-16
    const size_t off = (size_t)(col >> 4) * 4096 + (size_t)row * 16 + (col & 15);
    float sA = 0.f, sB = 0.f;
#pragma unroll
    for (int p = 1; p <= 8; p++) {
        const u32 hv = *(const u32*)(SH + (size_t)p * PS + off);
        const u32 lv = *(const u32*)(SL + (size_t)p * PS + off);
        sA += b2f((u16)(hv & 0xffff)) + b2f((u16)(lv & 0xffff));
        sB += b2f((u16)(hv >> 16))    + b2f((u16)(lv >> 16));
    }
    sA *= 0.125f; sB *= 0.125f;
    u16 hiA, loA, hiB, loB;
    split2(sA, hiA, loA); split2(sB, hiB, loB);
    *(u32*)(SH + 9 * (size_t)PS + off) = (u32)hiA | ((u32)hiB << 16);
    *(u32*)(SL + 9 * (size_t)PS + off) = (u32)loA | ((u32)loB << 16);
    const int oidx = row * H_ + col;
    *(float2*)(OUT + oidx) = make_float2(sA, sB);
    if (OUT2) *(float2*)(OUT2 + oidx) = make_float2(sA, sB);
}

extern "C" void kernel_launch(void* const* d_in, const int* in_sizes, int n_in,
                              void* d_out, int out_size, void* d_ws, size_t ws_size,
                              hipStream_t stream) {
    const float* X   = (const float*)d_in[0];  // [128, 256, 850]
    const float* HID = (const float*)d_in[1];  // [1, 256, 850]
    const float* W0  = (const float*)d_in[2];  // [1700, 1700]
    const float* WS  = (const float*)d_in[3];  // [8, 850, 1700]

    u16* WH = (u16*)d_ws;
    u16* WL = WH + (size_t)10 * WMS;
    u16* SH = WL + (size_t)10 * WMS;
    u16* SL = SH + (size_t)10 * PS;
    u16* XH = SL + (size_t)10 * PS;
    u16* XL = XH + (size_t)TB * SP;

    const size_t base_b = ((size_t)2 * 10 * WMS + (size_t)2 * 10 * PS) * 2;
    const size_t xw_b   = (size_t)TB * 1700 * 4;
    const size_t stage_b = (size_t)2 * TB * SP * 2;
    const size_t needA = base_b + stage_b + xw_b;   // ~403.7 MB
    const size_t needB = base_b + xw_b;             // ~290.4 MB

    const int tier = (ws_size >= needA) ? 0 : (ws_size >= needB) ? 1 : 2;
    float* XW = (tier == 0) ? (float*)(XL + (size_t)TB * SP)
                            : (float*)(SL + (size_t)10 * PS);

    float* OUT = (float*)d_out;

    transpose_w<<<dim3(14, 27, 10), 256, 0, stream>>>(W0, WS, WH, WL);
    init_kern<<<PS / 256, 256, 0, stream>>>(HID, SH, SL);
    zpad_kern<<<126, 256, 0, stream>>>(SH, SL);
    if (tier == 0) {
        stage_x<<<4096, 256, 0, stream>>>(X, XH, XL);
        xw_gemm<true ><<<dim3(14, 1, 512), 256, 0, stream>>>(WH, WL, XH, XL, X, XW);
    } else if (tier == 1) {
        xw_gemm<false><<<dim3(14, 1, 512), 256, 0, stream>>>(WH, WL, XH, XL, X, XW);
    }

    for (int t = 0; t < T_; t++) {
        if (tier <= 1)
            gemm_fat<0><<<dim3(32, 1, 8), 512, 0, stream>>>(
                WH, WL, SH, SL, XW + (size_t)t * B_ * 1700, 0);
        else
            gemm_fat<2><<<dim3(32, 1, 8), 512, 0, stream>>>(
                WH, WL, SH, SL, X + (size_t)t * BH, 0);
        gemm_fat<1><<<dim3(32, 2, 8), 512, 0, stream>>>(WH, WL, SH, SL, nullptr, 0);
        gemm_fat<1><<<dim3(32, 4, 8), 512, 0, stream>>>(WH, WL, SH, SL, nullptr, 2);
        gemm_fat<1><<<dim3(32, 2, 8), 512, 0, stream>>>(WH, WL, SH, SL, nullptr, 6);
        finalize_kern<<<425, 256, 0, stream>>>(
            SH, SL, OUT + (size_t)t * BH,
            (t == T_ - 1) ? (OUT + (size_t)T_ * BH) : (float*)nullptr);
    }
}